// Round 5
// baseline (193.577 us; speedup 1.0000x reference)
//
#include <hip/hip_runtime.h>
#include <hip/hip_fp16.h>
#include <math.h>

// CTC forward loss (warp-ctc semantics). T=1024, B=64, V=128, L=256, S=513.
//
// Round 7: DP wave-stacking. Same packed-FP32 DP step as Round 6, but the
// 64 batch-waves are launched as 8 blocks x 512 threads (8 waves/block ->
// 2 waves per SIMD). A single DP wave only issues ~58% of cycles (VALUBusy
// 3.63% vs 6.25% ceiling, R4 counters) — the recurrence dependency chains
// stall an otherwise-idle SIMD. A co-resident second batch-wave fills those
// bubbles; per-step elapsed should drop from ~146 cyc toward the 2x56 ~112
// cyc issue bound. No algorithmic change; waves remain fully independent.

#define L2E 1.4426950408889634f
#define LN2 0.6931471805599453f

constexpr int T   = 1024;
constexpr int B   = 64;
constexpr int V   = 128;
constexpr int L   = 256;
constexpr int RW  = 256;        // ushorts per P row: 256 label probs = 512 B
constexpr int TP  = T + 32;     // padded time rows per batch

typedef float v2f __attribute__((ext_vector_type(2)));

// ---- VOP3P packed-fp32 helpers (gfx90a+; full-rate dual fp32) ----
__device__ __forceinline__ v2f pk_add(v2f a, v2f b) {
  v2f d; asm("v_pk_add_f32 %0, %1, %2" : "=v"(d) : "v"(a), "v"(b)); return d;
}
__device__ __forceinline__ v2f pk_mul(v2f a, v2f b) {
  v2f d; asm("v_pk_mul_f32 %0, %1, %2" : "=v"(d) : "v"(a), "v"(b)); return d;
}
__device__ __forceinline__ v2f pk_fma(v2f a, v2f b, v2f c) {
  v2f d; asm("v_pk_fma_f32 %0, %1, %2, %3" : "=v"(d) : "v"(a), "v"(b), "v"(c));
  return d;
}

// ---- DPP helpers (gfx9 ctrl codes: 0x111+ row_shr, 0x138 wave_shr:1,
//      0x142 row_bcast15, 0x143 row_bcast31) ----
template <int CTRL>
__device__ __forceinline__ float fdpp0(float x) {        // invalid lanes -> 0
  return __int_as_float(__builtin_amdgcn_update_dpp(
      0, __float_as_int(x), CTRL, 0xf, 0xf, true));
}
template <int CTRL>
__device__ __forceinline__ float fdppk(float x) {        // invalid lanes -> keep
  return __int_as_float(__builtin_amdgcn_update_dpp(
      __float_as_int(x), __float_as_int(x), CTRL, 0xf, 0xf, false));
}

__device__ __forceinline__ float wave_bcast63(float x) {
  return __int_as_float(__builtin_amdgcn_readlane(__float_as_int(x), 63));
}

__device__ __forceinline__ float wave_max(float x) {     // any sign
  x = fmaxf(x, fdppk<0x111>(x));
  x = fmaxf(x, fdppk<0x112>(x));
  x = fmaxf(x, fdppk<0x114>(x));
  x = fmaxf(x, fdppk<0x118>(x));
  x = fmaxf(x, fdppk<0x142>(x));
  x = fmaxf(x, fdppk<0x143>(x));
  return wave_bcast63(x);
}
__device__ __forceinline__ float wave_sum_nn(float x) {  // x >= 0
  x += fdpp0<0x111>(x);
  x += fdpp0<0x112>(x);
  x += fdpp0<0x114>(x);
  x += fdpp0<0x118>(x);
  x += fdpp0<0x142>(x);
  x += fdpp0<0x143>(x);
  return wave_bcast63(x);
}

__device__ __forceinline__ float h2f(uint bits) {
  return __half2float(__ushort_as_half((ushort)bits));
}

// ---------------- prologue: emission probabilities ----------------
// One wave per (t, b) row. Softmax entirely in registers:
//   e_v = exp2(x_v * log2e - 32)   (fixed shift; |x| ~ N(0,1) so no overflow)
//   p_v = e_v * rcp(sum e)
// Lane l holds p_{2l}, p_{2l+1} packed as half2 (v_cvt_pkrtz). Label probs
// gathered cross-lane with ds_bpermute. Output PAIRED for the DP kernel:
//   u.x = (e0 | e2<<16), u.y = (e1 | e3<<16)  [labels 4l..4l+3].
__global__ __launch_bounds__(512) void ctc_probs_kernel(
    const float* __restrict__ acts,        // (T, B, V)
    const int* __restrict__ labels,        // (B, L)
    ushort* __restrict__ P,                // (B, TP, RW) fp16 bits, 512B rows
    float* __restrict__ Pbk) {             // (B, TP) duplicated fp32 pairs
  const int w    = threadIdx.x >> 6;
  const int lane = threadIdx.x & 63;
  const int t    = blockIdx.x * 8 + w;     // t in [0, TP)
  const int b    = blockIdx.y;
  ushort* prow = P + ((size_t)b * TP + t) * RW;

  if (t >= T) {                            // zero pad row (512 B + blank)
    uint2 z; z.x = 0u; z.y = 0u;
    *(uint2*)(prow + 4 * lane) = z;
    if (lane == 0) {
      v2f zp; zp.x = 0.f; zp.y = 0.f;
      *(v2f*)(Pbk + ((size_t)b * TP + t) * 2) = zp;
    }
    return;
  }

  const float* row = acts + ((size_t)t * B + b) * V;
  const float2 v2 = *(const float2*)(row + 2 * lane);
  const float e0 = exp2f(fmaf(v2.x, L2E, -32.0f));
  const float e1 = exp2f(fmaf(v2.y, L2E, -32.0f));
  const float sm = wave_sum_nn(e0 + e1);
  const float r  = __builtin_amdgcn_rcpf(sm);

  const auto pk = __builtin_amdgcn_cvt_pkrtz(e0 * r, e1 * r);
  uint hp;                                  // [p_{2l} | p_{2l+1} << 16]
  __builtin_memcpy(&hp, &pk, 4);

  // gather the 4 label probs this lane owns (labels 4l..4l+3)
  const int4 lv = *(const int4*)(labels + (size_t)b * L + 4 * lane);
  const uint g0 = (uint)__builtin_amdgcn_ds_bpermute((lv.x & ~1) * 2, (int)hp);
  const uint g1 = (uint)__builtin_amdgcn_ds_bpermute((lv.y & ~1) * 2, (int)hp);
  const uint g2 = (uint)__builtin_amdgcn_ds_bpermute((lv.z & ~1) * 2, (int)hp);
  const uint g3 = (uint)__builtin_amdgcn_ds_bpermute((lv.w & ~1) * 2, (int)hp);
  const uint h0 = (g0 >> ((lv.x & 1) << 4)) & 0xffffu;
  const uint h1 = (g1 >> ((lv.y & 1) << 4)) & 0xffffu;
  const uint h2 = (g2 >> ((lv.z & 1) << 4));
  const uint h3 = (g3 >> ((lv.w & 1) << 4));
  uint2 o;
  o.x = h0 | (h2 << 16);                    // pair (e0, e2)
  o.y = h1 | (h3 << 16);                    // pair (e1, e3)
  *(uint2*)(prow + 4 * lane) = o;
  if (lane == 0) {
    const float pb = e0 * r;                // vocab 0 = this lane's p0
    v2f bp; bp.x = pb; bp.y = pb;
    *(v2f*)(Pbk + ((size_t)b * TP + t) * 2) = bp;
  }
}

// ---------------- DP kernel: one wave per batch, 8 waves per block ----------------
// Lane l owns cells 8l..8l+7 as pairs P0=(c0,c4) P1=(c1,c5) P2=(c2,c6)
// P3=(c3,c7); lane 63 additionally owns cell 512 in a8. Waves are fully
// independent (per-wave DPP/readlane/atomics); 8 waves/block puts 2 waves
// on each SIMD so dependency stalls of one wave are filled by the other.
__global__ __launch_bounds__(512) void ctc_dp_kernel(
    const ushort* __restrict__ P,
    const float* __restrict__ Pbk,
    const int* __restrict__ labels,
    const int* __restrict__ act_lens,
    const int* __restrict__ label_lens,
    float* __restrict__ out) {
  const int b    = blockIdx.x * 8 + (threadIdx.x >> 6);
  const int lane = threadIdx.x & 63;
  const ushort* __restrict__ Pb = P + (size_t)b * TP * RW;
  const float*  __restrict__ Bk = Pbk + (size_t)b * TP * 2;

  // skip-transition flags for the 4 odd cells (labels 4l..4l+3)
  const int4 lv   = *(const int4*)(labels + (size_t)b * L + 4 * lane);
  const int prevw = __builtin_amdgcn_update_dpp(0, lv.w, 0x138, 0xf, 0xf, true);
  const float f0 = (lane > 0 && lv.x != 0 && lv.x != prevw) ? 1.f : 0.f;
  const float f1 = (lv.y != 0 && lv.y != lv.x) ? 1.f : 0.f;
  const float f2 = (lv.z != 0 && lv.z != lv.y) ? 1.f : 0.f;
  const float f3 = (lv.w != 0 && lv.w != lv.z) ? 1.f : 0.f;
  v2f F02; F02.x = f0; F02.y = f2;          // skips into P1 = (c1, c5)
  v2f F13; F13.x = f1; F13.y = f3;          // skips into P3 = (c3, c7)

  const int AL = act_lens[b];

  // ---- t=0 init (linear domain; unreachable cells = 0) ----
  v2f P0, P1, P2, P3;
  P0.x=0.f; P0.y=0.f; P1.x=0.f; P1.y=0.f;
  P2.x=0.f; P2.y=0.f; P3.x=0.f; P3.y=0.f;
  float a8 = 0.f;
  {
    const uint2 u0 = *(const uint2*)(Pb + 4 * lane);
    const v2f bk0  = *(const v2f*)(Bk);
    const float eb0 = bk0.x;                // blank prob at t=0
    const float e00 = h2f(u0.x);            // label-0 prob at t=0 (pair lo)
    if (lane == 0) { P0.x = eb0; P1.x = e00; }
  }
  int iacc = 0;        // accumulated log2 of renorm scales (wave-uniform)
  float pend = 1.0f;   // wave-maxed state max, measured 4 steps before apply

  // Packed step: 1 DPP + 4 pk_add + 2 pk_fma + 4 pk_mul (+ a8 scalar pair).
  auto step = [&](uint2 u, v2f eb) {
    const float pc = fdpp0<0x138>(P3.y);    // prev lane's c7 (lane0 -> 0)
    v2f Q; Q.x = pc; Q.y = P3.x;            // (c_{-1}, c3_old)
    v2f E02, E13;
    E02.x = h2f(u.x); E02.y = h2f(u.x >> 16);
    E13.x = h2f(u.y); E13.y = h2f(u.y >> 16);
    const v2f S0 = pk_add(P0, Q);           // (c0+pc,  c4+c3)
    const v2f S1 = pk_add(P1, P0);          // (c1+c0,  c5+c4)
    const v2f S2 = pk_add(P2, P1);          // (c2+c1,  c6+c5)
    const v2f S3 = pk_add(P3, P2);          // (c3+c2,  c7+c6)
    const v2f T1 = pk_fma(F02, Q,  S1);     // +f0*pc,  +f2*c3_old
    const v2f T3 = pk_fma(F13, P1, S3);     // +f1*c1_old, +f3*c5_old
    const float s8 = a8 + P3.y;             // cell 512 (valid on lane 63)
    P0 = pk_mul(S0, eb);
    P2 = pk_mul(S2, eb);
    P1 = pk_mul(T1, E02);
    P3 = pk_mul(T3, E13);
    a8 = s8 * eb.x;
  };

  auto measure = [&]() {                    // start wave-max; result used 4
    float m = fmaxf(fmaxf(fmaxf(P0.x, P0.y), fmaxf(P1.x, P1.y)),   // steps later
                    fmaxf(fmaxf(P2.x, P2.y), fmaxf(P3.x, P3.y)));
    m = fmaxf(m, a8);
    pend = wave_max(m);
  };
  auto apply = [&]() {                      // pow-2 scale, exact
    const uint mb = __float_as_uint(pend);
    int e = (int)((mb >> 23) & 0xffu); if (e < 1) e = 1;
    const float r = __uint_as_float((uint)(254 - e) << 23);
    iacc += (e - 127);
    v2f rr; rr.x = r; rr.y = r;
    P0 = pk_mul(P0, rr); P1 = pk_mul(P1, rr);
    P2 = pk_mul(P2, rr); P3 = pk_mul(P3, rr);
    a8 *= r;
  };

  // ---- prefetch pipeline: depth 16 (rows t .. t+15) ----
  uint2 ev[16];
  v2f   ebk[16];
  #pragma unroll
  for (int k = 0; k < 16; ++k) {
    ev[k]  = *(const uint2*)(Pb + (size_t)(1 + k) * RW + 4 * lane);
    ebk[k] = *(const v2f*)(Bk + (size_t)(1 + k) * 2);
  }

  const ushort* pf = Pb + (size_t)17 * RW;  // row t+16 for t=1
  const float*  bf = Bk + (size_t)17 * 2;
  int t0 = 1;
  for (int blk = 0; blk < 64; ++blk) {      // 64 x 16 = steps t=1..1024
    const bool fast = (t0 + 16 <= AL);
    if (fast) {
      #pragma unroll
      for (int k = 0; k < 16; ++k) {
        const uint2 u = ev[k];
        const v2f  eb = ebk[k];
        ev[k]  = *(const uint2*)(pf + (size_t)k * RW + 4 * lane);
        ebk[k] = *(const v2f*)(bf + (size_t)k * 2);
        step(u, eb);
        if (k == 3 || k == 11) measure();
        if (k == 7 || k == 15) apply();
      }
    } else {
      #pragma unroll
      for (int k = 0; k < 16; ++k) {
        const uint2 u = ev[k];
        const v2f  eb = ebk[k];
        ev[k]  = *(const uint2*)(pf + (size_t)k * RW + 4 * lane);
        ebk[k] = *(const v2f*)(bf + (size_t)k * 2);
        if ((t0 + k) < AL) step(u, eb);     // AL wave-uniform: scalar branch
        if (k == 3 || k == 11) measure();
        if (k == 7 || k == 15) apply();
      }
    }
    t0 += 16;
    pf += (size_t)16 * RW;
    bf += (size_t)16 * 2;
  }

  // ---- epilogue: -ln( (a[end] + a[end-1]) * 2^iacc ) ----
  // cell map: base+0=P0.x +1=P1.x +2=P2.x +3=P3.x +4=P0.y +5=P1.y +6=P2.y +7=P3.y
  const int end  = 2 * label_lens[b];
  const int base = 8 * lane;
  float sel = 0.f;
  if (base     == end || base     == end - 1) sel += P0.x;
  if (base + 1 == end || base + 1 == end - 1) sel += P1.x;
  if (base + 2 == end || base + 2 == end - 1) sel += P2.x;
  if (base + 3 == end || base + 3 == end - 1) sel += P3.x;
  if (base + 4 == end || base + 4 == end - 1) sel += P0.y;
  if (base + 5 == end || base + 5 == end - 1) sel += P1.y;
  if (base + 6 == end || base + 6 == end - 1) sel += P2.y;
  if (base + 7 == end || base + 7 == end - 1) sel += P3.y;
  if (lane == 63 && (end == 512 || end - 1 == 512)) sel += a8;
  sel = wave_sum_nn(sel);
  if (lane == 0) {
    const float cost = -((log2f(sel) + (float)iacc) * LN2);
    atomicAdd(out, cost);
  }
}

extern "C" void kernel_launch(void* const* d_in, const int* in_sizes, int n_in,
                              void* d_out, int out_size, void* d_ws, size_t ws_size,
                              hipStream_t stream) {
  const float* acts       = (const float*)d_in[0];
  const int*   labels     = (const int*)d_in[1];
  const int*   act_lens   = (const int*)d_in[2];
  const int*   label_lens = (const int*)d_in[3];
  float* out = (float*)d_out;
  ushort* P   = (ushort*)d_ws;                       // B*TP*RW*2 = 34.6 MB
  float*  Pbk = (float*)(P + (size_t)B * TP * RW);   // B*TP*8B   = 0.54 MB

  (void)hipMemsetAsync(out, 0, sizeof(float) * out_size, stream);
  ctc_probs_kernel<<<dim3(TP / 8, B), 512, 0, stream>>>(acts, labels, P, Pbk);
  ctc_dp_kernel<<<B / 8, 512, 0, stream>>>(P, Pbk, labels, act_lens, label_lens, out);
}

// Round 7
// 136.713 us; speedup vs baseline: 1.4159x; 1.4159x over previous
//
#include <hip/hip_runtime.h>
#include <hip/hip_fp16.h>
#include <math.h>

// CTC forward loss (warp-ctc semantics). T=1024, B=64, V=128, L=256, S=513.
//
// Round 8 (resubmit after infra failure): 64 blocks x 64 threads (R5's 8-CU
// concentration starved memory). DP uses an EXPLICIT asm prefetch pipeline:
// R4's VGPR=56 proved the compiler collapsed the source-level 16-deep
// prefetch (needs >=64 VGPRs) and exposed ~60 cyc/step of load latency.
// Here: inline-asm global_load_dwordx2/x4 into double-buffered register
// arrays, counted s_waitcnt vmcnt(24) once per 16-step block (never drain
// to 0), sched_barrier(0) after each wait (rule #18). Blanks ride the same
// asm pipeline as duplicated fp32 pairs (16B-aligned wave-uniform dwordx4).
// Tail prefetch clamps to block 63 so vmcnt counts stay constant.

#define L2E 1.4426950408889634f
#define LN2 0.6931471805599453f

constexpr int T   = 1024;
constexpr int B   = 64;
constexpr int V   = 128;
constexpr int L   = 256;
constexpr int RW  = 256;        // ushorts per P row: 256 label probs = 512 B
constexpr int TP  = T + 32;     // padded time rows per batch

typedef float v2f __attribute__((ext_vector_type(2)));
typedef unsigned int v2u __attribute__((ext_vector_type(2)));
typedef unsigned int v4u __attribute__((ext_vector_type(4)));

// ---- VOP3P packed-fp32 helpers (gfx90a+; full-rate dual fp32) ----
__device__ __forceinline__ v2f pk_add(v2f a, v2f b) {
  v2f d; asm("v_pk_add_f32 %0, %1, %2" : "=v"(d) : "v"(a), "v"(b)); return d;
}
__device__ __forceinline__ v2f pk_mul(v2f a, v2f b) {
  v2f d; asm("v_pk_mul_f32 %0, %1, %2" : "=v"(d) : "v"(a), "v"(b)); return d;
}
__device__ __forceinline__ v2f pk_fma(v2f a, v2f b, v2f c) {
  v2f d; asm("v_pk_fma_f32 %0, %1, %2, %3" : "=v"(d) : "v"(a), "v"(b), "v"(c));
  return d;
}

// ---- asm global loads into explicitly-held registers ----
template <int OFF>
__device__ __forceinline__ void gload2(v2u& d, uint voff, const void* base) {
  asm volatile("global_load_dwordx2 %0, %1, %2 offset:%3"
               : "=v"(d) : "v"(voff), "s"(base), "i"(OFF) : "memory");
}
template <int OFF>
__device__ __forceinline__ void gload4(v4u& d, uint voff, const void* base) {
  asm volatile("global_load_dwordx4 %0, %1, %2 offset:%3"
               : "=v"(d) : "v"(voff), "s"(base), "i"(OFF) : "memory");
}

// ---- DPP helpers (gfx9 ctrl codes: 0x111+ row_shr, 0x138 wave_shr:1,
//      0x142 row_bcast15, 0x143 row_bcast31) ----
template <int CTRL>
__device__ __forceinline__ float fdpp0(float x) {        // invalid lanes -> 0
  return __int_as_float(__builtin_amdgcn_update_dpp(
      0, __float_as_int(x), CTRL, 0xf, 0xf, true));
}
template <int CTRL>
__device__ __forceinline__ float fdppk(float x) {        // invalid lanes -> keep
  return __int_as_float(__builtin_amdgcn_update_dpp(
      __float_as_int(x), __float_as_int(x), CTRL, 0xf, 0xf, false));
}

__device__ __forceinline__ float wave_bcast63(float x) {
  return __int_as_float(__builtin_amdgcn_readlane(__float_as_int(x), 63));
}

__device__ __forceinline__ float wave_max(float x) {     // any sign
  x = fmaxf(x, fdppk<0x111>(x));
  x = fmaxf(x, fdppk<0x112>(x));
  x = fmaxf(x, fdppk<0x114>(x));
  x = fmaxf(x, fdppk<0x118>(x));
  x = fmaxf(x, fdppk<0x142>(x));
  x = fmaxf(x, fdppk<0x143>(x));
  return wave_bcast63(x);
}
__device__ __forceinline__ float wave_sum_nn(float x) {  // x >= 0
  x += fdpp0<0x111>(x);
  x += fdpp0<0x112>(x);
  x += fdpp0<0x114>(x);
  x += fdpp0<0x118>(x);
  x += fdpp0<0x142>(x);
  x += fdpp0<0x143>(x);
  return wave_bcast63(x);
}

__device__ __forceinline__ float h2f(uint bits) {
  return __half2float(__ushort_as_half((ushort)bits));
}

// ---------------- prologue: emission probabilities ----------------
// One wave per (t, b) row. Softmax entirely in registers; ds_bpermute label
// gathers. Output PAIRED for the DP: u.x=(e0|e2<<16), u.y=(e1|e3<<16).
// Blank(t) stored as a duplicated fp32 pair at pair index t+1 (so 16-step
// blocks start 16B-aligned for the DP's dwordx4 prefetch).
__global__ __launch_bounds__(512) void ctc_probs_kernel(
    const float* __restrict__ acts,        // (T, B, V)
    const int* __restrict__ labels,        // (B, L)
    ushort* __restrict__ P,                // (B, TP, RW) fp16 bits, 512B rows
    float* __restrict__ Pbk) {             // (B, TP pairs)
  const int w    = threadIdx.x >> 6;
  const int lane = threadIdx.x & 63;
  const int t    = blockIdx.x * 8 + w;     // t in [0, TP)
  const int b    = blockIdx.y;
  ushort* prow = P + ((size_t)b * TP + t) * RW;

  if (t >= T) {                            // zero pad P row (content unused)
    uint2 z; z.x = 0u; z.y = 0u;
    *(uint2*)(prow + 4 * lane) = z;
    return;
  }

  const float* row = acts + ((size_t)t * B + b) * V;
  const float2 v2 = *(const float2*)(row + 2 * lane);
  const float e0 = exp2f(fmaf(v2.x, L2E, -32.0f));
  const float e1 = exp2f(fmaf(v2.y, L2E, -32.0f));
  const float sm = wave_sum_nn(e0 + e1);
  const float r  = __builtin_amdgcn_rcpf(sm);

  const auto pk = __builtin_amdgcn_cvt_pkrtz(e0 * r, e1 * r);
  uint hp;                                  // [p_{2l} | p_{2l+1} << 16]
  __builtin_memcpy(&hp, &pk, 4);

  // gather the 4 label probs this lane owns (labels 4l..4l+3)
  const int4 lv = *(const int4*)(labels + (size_t)b * L + 4 * lane);
  const uint g0 = (uint)__builtin_amdgcn_ds_bpermute((lv.x & ~1) * 2, (int)hp);
  const uint g1 = (uint)__builtin_amdgcn_ds_bpermute((lv.y & ~1) * 2, (int)hp);
  const uint g2 = (uint)__builtin_amdgcn_ds_bpermute((lv.z & ~1) * 2, (int)hp);
  const uint g3 = (uint)__builtin_amdgcn_ds_bpermute((lv.w & ~1) * 2, (int)hp);
  const uint h0 = (g0 >> ((lv.x & 1) << 4)) & 0xffffu;
  const uint h1 = (g1 >> ((lv.y & 1) << 4)) & 0xffffu;
  const uint h2 = (g2 >> ((lv.z & 1) << 4));
  const uint h3 = (g3 >> ((lv.w & 1) << 4));
  uint2 o;
  o.x = h0 | (h2 << 16);                    // pair (e0, e2)
  o.y = h1 | (h3 << 16);                    // pair (e1, e3)
  *(uint2*)(prow + 4 * lane) = o;
  if (lane == 0) {
    const float pb = e0 * r;                // vocab 0 = this lane's p0
    v2f bp; bp.x = pb; bp.y = pb;
    *(v2f*)(Pbk + ((size_t)b * TP + t + 1) * 2) = bp;
  }
}

// ---------------- DP kernel: one wave per batch ----------------
// Lane l owns cells 8l..8l+7 as pairs P0=(c0,c4) P1=(c1,c5) P2=(c2,c6)
// P3=(c3,c7); lane 63 additionally owns cell 512 in a8.
__global__ __launch_bounds__(64, 1) void ctc_dp_kernel(
    const ushort* __restrict__ P,
    const float* __restrict__ Pbk,
    const int* __restrict__ labels,
    const int* __restrict__ act_lens,
    const int* __restrict__ label_lens,
    float* __restrict__ out) {
  const int b    = blockIdx.x;
  const int lane = threadIdx.x;
  const ushort* __restrict__ Pb = P + (size_t)b * TP * RW;
  const float*  __restrict__ Bk = Pbk + (size_t)b * TP * 2;

  // skip-transition flags for the 4 odd cells (labels 4l..4l+3)
  const int4 lv   = *(const int4*)(labels + (size_t)b * L + 4 * lane);
  const int prevw = __builtin_amdgcn_update_dpp(0, lv.w, 0x138, 0xf, 0xf, true);
  const float f0 = (lane > 0 && lv.x != 0 && lv.x != prevw) ? 1.f : 0.f;
  const float f1 = (lv.y != 0 && lv.y != lv.x) ? 1.f : 0.f;
  const float f2 = (lv.z != 0 && lv.z != lv.y) ? 1.f : 0.f;
  const float f3 = (lv.w != 0 && lv.w != lv.z) ? 1.f : 0.f;
  v2f F02; F02.x = f0; F02.y = f2;          // skips into P1 = (c1, c5)
  v2f F13; F13.x = f1; F13.y = f3;          // skips into P3 = (c3, c7)

  const int AL = act_lens[b];

  // ---- t=0 init (linear domain; unreachable cells = 0) ----
  v2f P0, P1, P2, P3;
  P0.x=0.f; P0.y=0.f; P1.x=0.f; P1.y=0.f;
  P2.x=0.f; P2.y=0.f; P3.x=0.f; P3.y=0.f;
  float a8 = 0.f;
  {
    const v2u u0 = *(const v2u*)(Pb + 4 * lane);
    const float eb0 = Bk[2];                // blank(t=0) at pair 1
    const float e00 = h2f(u0.x);            // label-0 prob at t=0 (pair lo)
    if (lane == 0) { P0.x = eb0; P1.x = e00; }
  }
  int iacc = 0;        // accumulated log2 of renorm scales (wave-uniform)
  float pend = 1.0f;   // wave-maxed state max, measured 4 steps before apply

  // Packed step: 1 DPP + 4 pk_add + 2 pk_fma + 4 pk_mul (+ a8 scalar pair).
  auto step = [&](v2u u, v2f eb) {
    const float pc = fdpp0<0x138>(P3.y);    // prev lane's c7 (lane0 -> 0)
    v2f Q; Q.x = pc; Q.y = P3.x;            // (c_{-1}, c3_old)
    v2f E02, E13;
    E02.x = h2f(u.x); E02.y = h2f(u.x >> 16);
    E13.x = h2f(u.y); E13.y = h2f(u.y >> 16);
    const v2f S0 = pk_add(P0, Q);           // (c0+pc,  c4+c3)
    const v2f S1 = pk_add(P1, P0);          // (c1+c0,  c5+c4)
    const v2f S2 = pk_add(P2, P1);          // (c2+c1,  c6+c5)
    const v2f S3 = pk_add(P3, P2);          // (c3+c2,  c7+c6)
    const v2f T1 = pk_fma(F02, Q,  S1);     // +f0*pc,  +f2*c3_old
    const v2f T3 = pk_fma(F13, P1, S3);     // +f1*c1_old, +f3*c5_old
    const float s8 = a8 + P3.y;             // cell 512 (valid on lane 63)
    P0 = pk_mul(S0, eb);
    P2 = pk_mul(S2, eb);
    P1 = pk_mul(T1, E02);
    P3 = pk_mul(T3, E13);
    a8 = s8 * eb.x;
  };

  auto measure = [&]() {                    // start wave-max; result used 4
    float m = fmaxf(fmaxf(fmaxf(P0.x, P0.y), fmaxf(P1.x, P1.y)),   // steps later
                    fmaxf(fmaxf(P2.x, P2.y), fmaxf(P3.x, P3.y)));
    m = fmaxf(m, a8);
    pend = wave_max(m);
  };
  auto apply = [&]() {                      // pow-2 scale, exact
    const uint mb = __float_as_uint(pend);
    int e = (int)((mb >> 23) & 0xffu); if (e < 1) e = 1;
    const float r = __uint_as_float((uint)(254 - e) << 23);
    iacc += (e - 127);
    v2f rr; rr.x = r; rr.y = r;
    P0 = pk_mul(P0, rr); P1 = pk_mul(P1, rr);
    P2 = pk_mul(P2, rr); P3 = pk_mul(P3, rr);
    a8 *= r;
  };

  // ---- explicit double-buffered asm prefetch: 24 loads per 16-step block
  //      (16x dwordx2 P rows + 8x dwordx4 blank pairs), vmcnt(24) waits ----
  v2u evA[16], evB[16];
  v4u bbA[8],  bbB[8];
  const uint lane8 = (uint)lane * 8u;

  auto issue_blk = [&](v2u (&ev)[16], v4u (&bb)[8], int pblk) {
    const uint pv  = (uint)((1 + 16 * pblk) * 512) + lane8;
    const uint pv2 = pv + 4096u;
    gload2<0>(ev[0], pv, Pb);    gload2<512>(ev[1], pv, Pb);
    gload2<1024>(ev[2], pv, Pb); gload2<1536>(ev[3], pv, Pb);
    gload2<2048>(ev[4], pv, Pb); gload2<2560>(ev[5], pv, Pb);
    gload2<3072>(ev[6], pv, Pb); gload2<3584>(ev[7], pv, Pb);
    gload2<0>(ev[8], pv2, Pb);    gload2<512>(ev[9], pv2, Pb);
    gload2<1024>(ev[10], pv2, Pb); gload2<1536>(ev[11], pv2, Pb);
    gload2<2048>(ev[12], pv2, Pb); gload2<2560>(ev[13], pv2, Pb);
    gload2<3072>(ev[14], pv2, Pb); gload2<3584>(ev[15], pv2, Pb);
    const uint bv = (uint)((2 + 16 * pblk) * 8);   // 16B-aligned
    gload4<0>(bb[0], bv, Bk);   gload4<16>(bb[1], bv, Bk);
    gload4<32>(bb[2], bv, Bk);  gload4<48>(bb[3], bv, Bk);
    gload4<64>(bb[4], bv, Bk);  gload4<80>(bb[5], bv, Bk);
    gload4<96>(bb[6], bv, Bk);  gload4<112>(bb[7], bv, Bk);
  };

  auto compute_blk = [&](v2u (&ev)[16], v4u (&bb)[8], int tb, bool fast) {
    if (fast) {
      #pragma unroll
      for (int k = 0; k < 16; ++k) {
        const v4u q = bb[k >> 1];
        v2f eb;
        if (k & 1) { eb.x = __uint_as_float(q.z); eb.y = __uint_as_float(q.w); }
        else       { eb.x = __uint_as_float(q.x); eb.y = __uint_as_float(q.y); }
        step(ev[k], eb);
        if (k == 3 || k == 11) measure();
        if (k == 7 || k == 15) apply();
      }
    } else {
      #pragma unroll
      for (int k = 0; k < 16; ++k) {
        const v4u q = bb[k >> 1];
        v2f eb;
        if (k & 1) { eb.x = __uint_as_float(q.z); eb.y = __uint_as_float(q.w); }
        else       { eb.x = __uint_as_float(q.x); eb.y = __uint_as_float(q.y); }
        if ((tb + k) < AL) step(ev[k], eb); // AL wave-uniform: scalar branch
        if (k == 3 || k == 11) measure();
        if (k == 7 || k == 15) apply();
      }
    }
  };

  issue_blk(evA, bbA, 0);
  issue_blk(evB, bbB, 1);

  int t0 = 1;
  #pragma unroll 1
  for (int it = 0; it < 32; ++it) {
    asm volatile("s_waitcnt vmcnt(24)" ::: "memory");   // block 2it ready
    __builtin_amdgcn_sched_barrier(0);
    compute_blk(evA, bbA, t0, (t0 + 16) <= AL);
    { int nb = 2 * it + 2; if (nb > 63) nb = 63; issue_blk(evA, bbA, nb); }
    asm volatile("s_waitcnt vmcnt(24)" ::: "memory");   // block 2it+1 ready
    __builtin_amdgcn_sched_barrier(0);
    compute_blk(evB, bbB, t0 + 16, (t0 + 32) <= AL);
    { int nb = 2 * it + 3; if (nb > 63) nb = 63; issue_blk(evB, bbB, nb); }
    t0 += 32;
  }

  // ---- epilogue: -ln( (a[end] + a[end-1]) * 2^iacc ) ----
  // cell map: base+0=P0.x +1=P1.x +2=P2.x +3=P3.x +4=P0.y +5=P1.y +6=P2.y +7=P3.y
  const int end  = 2 * label_lens[b];
  const int base = 8 * lane;
  float sel = 0.f;
  if (base     == end || base     == end - 1) sel += P0.x;
  if (base + 1 == end || base + 1 == end - 1) sel += P1.x;
  if (base + 2 == end || base + 2 == end - 1) sel += P2.x;
  if (base + 3 == end || base + 3 == end - 1) sel += P3.x;
  if (base + 4 == end || base + 4 == end - 1) sel += P0.y;
  if (base + 5 == end || base + 5 == end - 1) sel += P1.y;
  if (base + 6 == end || base + 6 == end - 1) sel += P2.y;
  if (base + 7 == end || base + 7 == end - 1) sel += P3.y;
  if (lane == 63 && (end == 512 || end - 1 == 512)) sel += a8;
  sel = wave_sum_nn(sel);
  if (lane == 0) {
    const float cost = -((log2f(sel) + (float)iacc) * LN2);
    atomicAdd(out, cost);
  }
}

extern "C" void kernel_launch(void* const* d_in, const int* in_sizes, int n_in,
                              void* d_out, int out_size, void* d_ws, size_t ws_size,
                              hipStream_t stream) {
  const float* acts       = (const float*)d_in[0];
  const int*   labels     = (const int*)d_in[1];
  const int*   act_lens   = (const int*)d_in[2];
  const int*   label_lens = (const int*)d_in[3];
  float* out = (float*)d_out;
  ushort* P   = (ushort*)d_ws;                       // B*TP*512B = 34.6 MB
  float*  Pbk = (float*)(P + (size_t)B * TP * RW);   // B*TP*8B   = 0.54 MB

  (void)hipMemsetAsync(out, 0, sizeof(float) * out_size, stream);
  ctc_probs_kernel<<<dim3(TP / 8, B), 512, 0, stream>>>(acts, labels, P, Pbk);
  ctc_dp_kernel<<<B, 64, 0, stream>>>(P, Pbk, labels, act_lens, label_lens, out);
}